// Round 1
// baseline (1164.488 us; speedup 1.0000x reference)
//
#include <hip/hip_runtime.h>
#include <cstddef>

// db4 filters (cross-correlation taps, matching lax.conv_general_dilated)
__constant__ float c_dec_lo[8] = {
    -0.010597401785069032f, 0.0328830116668852f, 0.030841381835560764f,
    -0.18703481171888114f, -0.027983769416859854f, 0.6308807679298589f,
    0.7148465705529157f, 0.2303778133088965f};
__constant__ float c_dec_hi[8] = {
    -0.2303778133088965f, 0.7148465705529157f, -0.6308807679298589f,
    -0.027983769416859854f, 0.18703481171888114f, 0.030841381835560764f,
    -0.0328830116668852f, -0.010597401785069032f};
__constant__ float c_rec_lo[8] = {
    0.2303778133088965f, 0.7148465705529157f, 0.6308807679298589f,
    -0.027983769416859854f, -0.18703481171888114f, 0.030841381835560764f,
    0.0328830116668852f, -0.010597401785069032f};
__constant__ float c_rec_hi[8] = {
    -0.010597401785069032f, -0.0328830116668852f, 0.030841381835560764f,
    0.18703481171888114f, -0.027983769416859854f, -0.6308807679298589f,
    0.7148465705529157f, -0.2303778133088965f};

__device__ __forceinline__ float gelu_tanh(float x) {
    // jax.nn.gelu default (approximate=True): 0.5x(1+tanh(sqrt(2/pi)(x+0.044715x^3)))
    float u = 0.7978845608028654f * (x + 0.044715f * x * x * x);
    float e = __expf(2.f * u);
    float t = 1.f - 2.f / (e + 1.f);
    return 0.5f * x * (1.f + t);
}

// Depthwise stride-2 analysis conv: lo[t]=sum_k dec_lo[k]*x[2t+k-3], same for hi.
// Lout = 1<<lshift, Lin = 2*Lout.
__global__ __launch_bounds__(256) void dwt_kernel(
    const float* __restrict__ X, float* __restrict__ LO, float* __restrict__ HI,
    int Lin, int lshift, int total)
{
    int idx = blockIdx.x * 256 + threadIdx.x;
    if (idx >= total) return;
    int Lout = 1 << lshift;
    int t = idx & (Lout - 1);
    int bc = idx >> lshift;
    const float* x = X + ((size_t)bc << (lshift + 1));
    int j0 = 2 * t - 3;
    float lo = 0.f, hi = 0.f;
#pragma unroll
    for (int k = 0; k < 8; ++k) {
        int j = j0 + k;
        float v = (j >= 0 && j < Lin) ? x[j] : 0.f;
        lo += c_dec_lo[k] * v;
        hi += c_dec_hi[k] * v;
    }
    LO[idx] = lo;
    HI[idx] = hi;
}

// Synthesis (conv_transpose stride 2, pad 3): y[t] = sum_{j in taps} rec[j]*in[(t+3-j)/2]
// where j has parity (t+1)&1. Lout = 2*Lin = 1<<lshift.
__global__ __launch_bounds__(256) void idwt_kernel(
    const float* __restrict__ A, const float* __restrict__ D, float* __restrict__ Y,
    int Lin, int lshift, int total)
{
    int idx = blockIdx.x * 256 + threadIdx.x;
    if (idx >= total) return;
    int Lout = 1 << lshift;
    int t = idx & (Lout - 1);
    int bc = idx >> lshift;
    size_t base = (size_t)bc << (lshift - 1);
    const float* a = A + base;
    const float* d = D + base;
    int j0 = (t & 1) ? 0 : 1;
    float acc = 0.f;
#pragma unroll
    for (int m = 0; m < 4; ++m) {
        int j = j0 + 2 * m;
        int i = (t + 3 - j) >> 1;
        if (i >= 0 && i < Lin)
            acc += c_rec_lo[j] * a[i] + c_rec_hi[j] * d[i];
    }
    Y[idx] = acc;
}

// Out[b,o,n] = epilogue( sum_c W[o,c]*X[b,c,n] + bias[o] )
// MODE 0: epilogue = gelu    MODE 1: epilogue = + X0[b,o,n] (residual; in-place safe)
// 128x128 tile, BK=16, 256 threads, 8x8 per-thread micro-tile, fp32.
template <int MODE>
__global__ __launch_bounds__(256) void gemm_kernel(
    const float* __restrict__ X, const float* __restrict__ W,
    const float* __restrict__ bias, const float* __restrict__ X0,
    float* __restrict__ Out, int L)
{
    __shared__ float As[16][132];
    __shared__ float Bs[16][132];
    const int tid = threadIdx.x;
    const int b = blockIdx.z;
    const int m0 = blockIdx.x * 128;
    const int n0 = blockIdx.y * 128;
    const size_t cb = (size_t)b * 256 * (size_t)L;
    const float* Xb = X + cb;

    const int ao = tid >> 1;          // 0..127 (W row within tile)
    const int ac = (tid & 1) * 8;     // 0 or 8 (k offset)
    const int bk = tid >> 5;          // 0..7   (k row)
    const int bn = (tid & 31) * 4;    // col offset
    const int tr = tid & 15;          // micro-tile row group
    const int tc = tid >> 4;          // micro-tile col group

    float acc[8][8];
#pragma unroll
    for (int i = 0; i < 8; ++i)
#pragma unroll
        for (int j = 0; j < 8; ++j) acc[i][j] = 0.f;

    for (int k0 = 0; k0 < 256; k0 += 16) {
        float4 a0 = *(const float4*)&W[(m0 + ao) * 256 + k0 + ac];
        float4 a1 = *(const float4*)&W[(m0 + ao) * 256 + k0 + ac + 4];
        float4 b0 = *(const float4*)&Xb[(size_t)(k0 + bk) * L + n0 + bn];
        float4 b1 = *(const float4*)&Xb[(size_t)(k0 + bk + 8) * L + n0 + bn];
        As[ac + 0][ao] = a0.x; As[ac + 1][ao] = a0.y;
        As[ac + 2][ao] = a0.z; As[ac + 3][ao] = a0.w;
        As[ac + 4][ao] = a1.x; As[ac + 5][ao] = a1.y;
        As[ac + 6][ao] = a1.z; As[ac + 7][ao] = a1.w;
        *(float4*)&Bs[bk][bn] = b0;
        *(float4*)&Bs[bk + 8][bn] = b1;
        __syncthreads();
#pragma unroll
        for (int k = 0; k < 16; ++k) {
            float av[8], bv[8];
            *(float4*)&av[0] = *(const float4*)&As[k][tr * 8];
            *(float4*)&av[4] = *(const float4*)&As[k][tr * 8 + 4];
            *(float4*)&bv[0] = *(const float4*)&Bs[k][tc * 8];
            *(float4*)&bv[4] = *(const float4*)&Bs[k][tc * 8 + 4];
#pragma unroll
            for (int i = 0; i < 8; ++i)
#pragma unroll
                for (int j = 0; j < 8; ++j) acc[i][j] += av[i] * bv[j];
        }
        __syncthreads();
    }

    float* Outb = Out + cb;
    const float* X0b = X0 + cb;  // only dereferenced when MODE==1
#pragma unroll
    for (int i = 0; i < 8; ++i) {
        int m = m0 + tr * 8 + i;
        float bb = bias[m];
        size_t off = (size_t)m * L + n0 + tc * 8;
        float o[8];
        if (MODE == 1) {
            float4 r0 = *(const float4*)&X0b[off];
            float4 r1 = *(const float4*)&X0b[off + 4];
            o[0] = r0.x; o[1] = r0.y; o[2] = r0.z; o[3] = r0.w;
            o[4] = r1.x; o[5] = r1.y; o[6] = r1.z; o[7] = r1.w;
        } else {
#pragma unroll
            for (int j = 0; j < 8; ++j) o[j] = 0.f;
        }
#pragma unroll
        for (int j = 0; j < 8; ++j) {
            float v = acc[i][j] + bb;
            if (MODE == 0) v = gelu_tanh(v);
            o[j] += (MODE == 0) ? (v - o[j]) : v;  // MODE0: o=v, MODE1: o=x0+v
        }
        *(float4*)&Outb[off]     = make_float4(o[0], o[1], o[2], o[3]);
        *(float4*)&Outb[off + 4] = make_float4(o[4], o[5], o[6], o[7]);
    }
}

// LayerNorm over channel axis of [16,256,8192]: v = Y + S, then (v-mu)*rsqrt(var+eps)*g+b.
// Block = 256 threads handles one b and 32 consecutive l positions; v staged in LDS.
__global__ __launch_bounds__(256) void ln_kernel(
    float* __restrict__ Y, const float* __restrict__ S,
    const float* __restrict__ g, const float* __restrict__ be)
{
    __shared__ float v[256][32];
    __shared__ float ps[8][32];
    __shared__ float pq[8][32];
    __shared__ float smu[32], srs[32];
    const int tid = threadIdx.x;
    const int lp = tid & 31;
    const int c0 = tid >> 5;  // 0..7
    const int b = blockIdx.y;
    const size_t base = (size_t)b * 256 * 8192 + (size_t)blockIdx.x * 32 + lp;
    float s = 0.f, q = 0.f;
#pragma unroll 4
    for (int cc = 0; cc < 32; ++cc) {
        int c = (c0 << 5) + cc;
        size_t a = base + (size_t)c * 8192;
        float val = Y[a] + S[a];
        v[c][lp] = val;
        s += val;
        q += val * val;
    }
    ps[c0][lp] = s;
    pq[c0][lp] = q;
    __syncthreads();
    if (tid < 32) {
        float S_ = 0.f, Q_ = 0.f;
#pragma unroll
        for (int i = 0; i < 8; ++i) { S_ += ps[i][tid]; Q_ += pq[i][tid]; }
        float m = S_ * (1.f / 256.f);
        float var = Q_ * (1.f / 256.f) - m * m;
        smu[tid] = m;
        srs[tid] = rsqrtf(var + 1e-5f);
    }
    __syncthreads();
    float mu = smu[lp], rs = srs[lp];
#pragma unroll 4
    for (int cc = 0; cc < 32; ++cc) {
        int c = (c0 << 5) + cc;
        size_t a = base + (size_t)c * 8192;
        Y[a] = (v[c][lp] - mu) * rs * g[c] + be[c];
    }
}

extern "C" void kernel_launch(void* const* d_in, const int* in_sizes, int n_in,
                              void* d_out, int out_size, void* d_ws, size_t ws_size,
                              hipStream_t stream) {
    const float* x     = (const float*)d_in[0];
    const float* ab_w1 = (const float*)d_in[1];
    const float* ab_b1 = (const float*)d_in[2];
    const float* ab_w2 = (const float*)d_in[3];
    const float* ab_b2 = (const float*)d_in[4];
    const float* db_w1 = (const float*)d_in[5];
    const float* db_b1 = (const float*)d_in[6];
    const float* db_w2 = (const float*)d_in[7];
    const float* db_b2 = (const float*)d_in[8];
    const float* ln_g  = (const float*)d_in[9];
    const float* ln_b  = (const float*)d_in[10];

    const int B = 16;
    // workspace layout (fp32): A1,D1 @ L=4096; A2,D2 @ 2048; A3,D3 @ 1024  => 224 MiB
    float* A1 = (float*)d_ws;
    float* D1 = A1 + (size_t)B * 256 * 4096;
    float* A2 = D1 + (size_t)B * 256 * 4096;
    float* D2 = A2 + (size_t)B * 256 * 2048;
    float* A3 = D2 + (size_t)B * 256 * 2048;
    float* D3 = A3 + (size_t)B * 256 * 1024;
    float* H   = (float*)d_out;  // hidden scratch (<=64 MiB used; overwritten later)
    float* out = (float*)d_out;

    // ---- analysis ----
    {   // level 1: 8192 -> 4096
        int total = B * 256 * 4096;
        dwt_kernel<<<total / 256, 256, 0, stream>>>(x, A1, D1, 8192, 12, total);
    }
    gemm_kernel<0><<<dim3(2, 4096 / 128, B), 256, 0, stream>>>(D1, db_w1, db_b1, nullptr, H, 4096);
    gemm_kernel<1><<<dim3(2, 4096 / 128, B), 256, 0, stream>>>(H, db_w2, db_b2, D1, D1, 4096);
    {   // level 2: 4096 -> 2048
        int total = B * 256 * 2048;
        dwt_kernel<<<total / 256, 256, 0, stream>>>(A1, A2, D2, 4096, 11, total);
    }
    gemm_kernel<0><<<dim3(2, 2048 / 128, B), 256, 0, stream>>>(D2, db_w1, db_b1, nullptr, H, 2048);
    gemm_kernel<1><<<dim3(2, 2048 / 128, B), 256, 0, stream>>>(H, db_w2, db_b2, D2, D2, 2048);
    {   // level 3: 2048 -> 1024
        int total = B * 256 * 1024;
        dwt_kernel<<<total / 256, 256, 0, stream>>>(A2, A3, D3, 2048, 10, total);
    }
    gemm_kernel<0><<<dim3(2, 1024 / 128, B), 256, 0, stream>>>(D3, db_w1, db_b1, nullptr, H, 1024);
    gemm_kernel<1><<<dim3(2, 1024 / 128, B), 256, 0, stream>>>(H, db_w2, db_b2, D3, D3, 1024);
    // approx res block (ab_*)
    gemm_kernel<0><<<dim3(2, 1024 / 128, B), 256, 0, stream>>>(A3, ab_w1, ab_b1, nullptr, H, 1024);
    gemm_kernel<1><<<dim3(2, 1024 / 128, B), 256, 0, stream>>>(H, ab_w2, ab_b2, A3, A3, 1024);

    // ---- synthesis ----
    {   // 1024 -> 2048, into A2 (free)
        int total = B * 256 * 2048;
        idwt_kernel<<<total / 256, 256, 0, stream>>>(A3, D3, A2, 1024, 11, total);
    }
    {   // 2048 -> 4096, into A1 (free)
        int total = B * 256 * 4096;
        idwt_kernel<<<total / 256, 256, 0, stream>>>(A2, D2, A1, 2048, 12, total);
    }
    {   // 4096 -> 8192, into d_out
        int total = B * 256 * 8192;
        idwt_kernel<<<total / 256, 256, 0, stream>>>(A1, D1, out, 4096, 13, total);
    }
    // ---- skip + layer norm (in place on d_out) ----
    ln_kernel<<<dim3(8192 / 32, B), 256, 0, stream>>>(out, x, ln_g, ln_b);
}

// Round 2
// 951.107 us; speedup vs baseline: 1.2244x; 1.2244x over previous
//
#include <hip/hip_runtime.h>
#include <cstddef>

// db4 filters (cross-correlation taps, matching lax.conv_general_dilated)
__constant__ float c_dec_lo[8] = {
    -0.010597401785069032f, 0.0328830116668852f, 0.030841381835560764f,
    -0.18703481171888114f, -0.027983769416859854f, 0.6308807679298589f,
    0.7148465705529157f, 0.2303778133088965f};
__constant__ float c_dec_hi[8] = {
    -0.2303778133088965f, 0.7148465705529157f, -0.6308807679298589f,
    -0.027983769416859854f, 0.18703481171888114f, 0.030841381835560764f,
    -0.0328830116668852f, -0.010597401785069032f};
__constant__ float c_rec_lo[8] = {
    0.2303778133088965f, 0.7148465705529157f, 0.6308807679298589f,
    -0.027983769416859854f, -0.18703481171888114f, 0.030841381835560764f,
    0.0328830116668852f, -0.010597401785069032f};
__constant__ float c_rec_hi[8] = {
    -0.010597401785069032f, -0.0328830116668852f, 0.030841381835560764f,
    0.18703481171888114f, -0.027983769416859854f, -0.6308807679298589f,
    0.7148465705529157f, -0.2303778133088965f};

__device__ __forceinline__ float gelu_tanh(float x) {
    // jax.nn.gelu default (approximate=True)
    float u = 0.7978845608028654f * (x + 0.044715f * x * x * x);
    float e = __expf(2.f * u);
    float t = 1.f - 2.f / (e + 1.f);
    return 0.5f * x * (1.f + t);
}

// ---------------- DWT: depthwise stride-2 analysis conv ----------------
// lo[t] = sum_k dec_lo[k] * x[2t-3+k]. One block = 1024 outputs of one (b,c) row.
// LDS layout: value at global j stored at sx[li&3][li>>2], li = j - (2*T0-4).
__global__ __launch_bounds__(256) void dwt_kernel(
    const float* __restrict__ X, float* __restrict__ LO, float* __restrict__ HI,
    int Lout_shift)
{
    const int Lout = 1 << Lout_shift;
    const int Lin = Lout << 1;
    const int tid = threadIdx.x;
    const int T0 = blockIdx.x << 10;
    const size_t rin = (size_t)blockIdx.y * (size_t)Lin;
    const size_t rout = (size_t)blockIdx.y * (size_t)Lout;
    __shared__ float sx[4][520];  // 514 chunks used
    const int g0 = 2 * T0 - 4;
    for (int k = tid; k < 514; k += 256) {
        int gb = g0 + 4 * k;
        float4 v;
        if (gb >= 0 && gb + 4 <= Lin) {
            v = *(const float4*)&X[rin + gb];
        } else {
            v.x = (gb + 0 >= 0 && gb + 0 < Lin) ? X[rin + gb + 0] : 0.f;
            v.y = (gb + 1 >= 0 && gb + 1 < Lin) ? X[rin + gb + 1] : 0.f;
            v.z = (gb + 2 >= 0 && gb + 2 < Lin) ? X[rin + gb + 2] : 0.f;
            v.w = (gb + 3 >= 0 && gb + 3 < Lin) ? X[rin + gb + 3] : 0.f;
        }
        sx[0][k] = v.x; sx[1][k] = v.y; sx[2][k] = v.z; sx[3][k] = v.w;
    }
    __syncthreads();
    const int u = tid;  // outputs t = T0 + 4u .. +3; needs li in [8u+1, 8u+14]
    float xv[14];
#pragma unroll
    for (int n = 0; n < 14; ++n)
        xv[n] = sx[(1 + n) & 3][2 * u + ((1 + n) >> 2)];
    float lo[4], hi[4];
#pragma unroll
    for (int e = 0; e < 4; ++e) {
        float l = 0.f, h = 0.f;
#pragma unroll
        for (int kk = 0; kk < 8; ++kk) {
            float v = xv[2 * e + kk];
            l += c_dec_lo[kk] * v;
            h += c_dec_hi[kk] * v;
        }
        lo[e] = l; hi[e] = h;
    }
    size_t o = rout + T0 + 4 * u;
    *(float4*)&LO[o] = make_float4(lo[0], lo[1], lo[2], lo[3]);
    *(float4*)&HI[o] = make_float4(hi[0], hi[1], hi[2], hi[3]);
}

// ---------------- IDWT: conv_transpose stride 2 ----------------
// y[t] = sum_{j parity (t+1)&1} rec[j]*in[(t+3-j)/2]. One block = 2048 outputs of one row.
// LDS: value at global i stored at sa[li&3][li>>2], li = i - (T0/2 - 4).
__global__ __launch_bounds__(256) void idwt_kernel(
    const float* __restrict__ A, const float* __restrict__ D,
    const float* __restrict__ SKIP, float* __restrict__ Y, int Lout_shift)
{
    const int Lout = 1 << Lout_shift;
    const int Lin = Lout >> 1;
    const int tid = threadIdx.x;
    const int T0 = blockIdx.x << 11;
    const size_t rin = (size_t)blockIdx.y * (size_t)Lin;
    const size_t rout = (size_t)blockIdx.y * (size_t)Lout;
    __shared__ float sa[4][264], sd[4][264];  // 258 chunks used
    const int g0 = (T0 >> 1) - 4;
    for (int k = tid; k < 258; k += 256) {
        int gb = g0 + 4 * k;
        float4 va, vd;
        if (gb >= 0 && gb + 4 <= Lin) {
            va = *(const float4*)&A[rin + gb];
            vd = *(const float4*)&D[rin + gb];
        } else {
            const float* a = A + rin;
            const float* d = D + rin;
            va.x = (gb + 0 >= 0 && gb + 0 < Lin) ? a[gb + 0] : 0.f;
            va.y = (gb + 1 >= 0 && gb + 1 < Lin) ? a[gb + 1] : 0.f;
            va.z = (gb + 2 >= 0 && gb + 2 < Lin) ? a[gb + 2] : 0.f;
            va.w = (gb + 3 >= 0 && gb + 3 < Lin) ? a[gb + 3] : 0.f;
            vd.x = (gb + 0 >= 0 && gb + 0 < Lin) ? d[gb + 0] : 0.f;
            vd.y = (gb + 1 >= 0 && gb + 1 < Lin) ? d[gb + 1] : 0.f;
            vd.z = (gb + 2 >= 0 && gb + 2 < Lin) ? d[gb + 2] : 0.f;
            vd.w = (gb + 3 >= 0 && gb + 3 < Lin) ? d[gb + 3] : 0.f;
        }
        sa[0][k] = va.x; sa[1][k] = va.y; sa[2][k] = va.z; sa[3][k] = va.w;
        sd[0][k] = vd.x; sd[1][k] = vd.y; sd[2][k] = vd.z; sd[3][k] = vd.w;
    }
    __syncthreads();
    const int u = tid;  // outputs t = T0 + 8u .. +7; needs li in [4u+2, 4u+9]
    float Aa[8], Dd[8];
#pragma unroll
    for (int n = 0; n < 8; ++n) {
        int li = 4 * u + 2 + n;
        Aa[n] = sa[(2 + n) & 3][li >> 2];
        Dd[n] = sd[(2 + n) & 3][li >> 2];
    }
    float o[8];
#pragma unroll
    for (int e = 0; e < 4; ++e) {
        o[2 * e] =
            c_rec_lo[1] * Aa[e + 3] + c_rec_lo[3] * Aa[e + 2] +
            c_rec_lo[5] * Aa[e + 1] + c_rec_lo[7] * Aa[e] +
            c_rec_hi[1] * Dd[e + 3] + c_rec_hi[3] * Dd[e + 2] +
            c_rec_hi[5] * Dd[e + 1] + c_rec_hi[7] * Dd[e];
        o[2 * e + 1] =
            c_rec_lo[0] * Aa[e + 4] + c_rec_lo[2] * Aa[e + 3] +
            c_rec_lo[4] * Aa[e + 2] + c_rec_lo[6] * Aa[e + 1] +
            c_rec_hi[0] * Dd[e + 4] + c_rec_hi[2] * Dd[e + 3] +
            c_rec_hi[4] * Dd[e + 2] + c_rec_hi[6] * Dd[e + 1];
    }
    size_t ob = rout + T0 + 8 * u;
    if (SKIP != nullptr) {
        float4 s0 = *(const float4*)&SKIP[ob];
        float4 s1 = *(const float4*)&SKIP[ob + 4];
        o[0] += s0.x; o[1] += s0.y; o[2] += s0.z; o[3] += s0.w;
        o[4] += s1.x; o[5] += s1.y; o[6] += s1.z; o[7] += s1.w;
    }
    *(float4*)&Y[ob]     = make_float4(o[0], o[1], o[2], o[3]);
    *(float4*)&Y[ob + 4] = make_float4(o[4], o[5], o[6], o[7]);
}

// ---------------- GEMM (fp32, unchanged this round) ----------------
template <int MODE>
__global__ __launch_bounds__(256) void gemm_kernel(
    const float* __restrict__ X, const float* __restrict__ W,
    const float* __restrict__ bias, const float* __restrict__ X0,
    float* __restrict__ Out, int L)
{
    __shared__ float As[16][132];
    __shared__ float Bs[16][132];
    const int tid = threadIdx.x;
    const int b = blockIdx.z;
    const int m0 = blockIdx.x * 128;
    const int n0 = blockIdx.y * 128;
    const size_t cb = (size_t)b * 256 * (size_t)L;
    const float* Xb = X + cb;

    const int ao = tid >> 1;
    const int ac = (tid & 1) * 8;
    const int bk = tid >> 5;
    const int bn = (tid & 31) * 4;
    const int tr = tid & 15;
    const int tc = tid >> 4;

    float acc[8][8];
#pragma unroll
    for (int i = 0; i < 8; ++i)
#pragma unroll
        for (int j = 0; j < 8; ++j) acc[i][j] = 0.f;

    for (int k0 = 0; k0 < 256; k0 += 16) {
        float4 a0 = *(const float4*)&W[(m0 + ao) * 256 + k0 + ac];
        float4 a1 = *(const float4*)&W[(m0 + ao) * 256 + k0 + ac + 4];
        float4 b0 = *(const float4*)&Xb[(size_t)(k0 + bk) * L + n0 + bn];
        float4 b1 = *(const float4*)&Xb[(size_t)(k0 + bk + 8) * L + n0 + bn];
        As[ac + 0][ao] = a0.x; As[ac + 1][ao] = a0.y;
        As[ac + 2][ao] = a0.z; As[ac + 3][ao] = a0.w;
        As[ac + 4][ao] = a1.x; As[ac + 5][ao] = a1.y;
        As[ac + 6][ao] = a1.z; As[ac + 7][ao] = a1.w;
        *(float4*)&Bs[bk][bn] = b0;
        *(float4*)&Bs[bk + 8][bn] = b1;
        __syncthreads();
#pragma unroll
        for (int k = 0; k < 16; ++k) {
            float av[8], bv[8];
            *(float4*)&av[0] = *(const float4*)&As[k][tr * 8];
            *(float4*)&av[4] = *(const float4*)&As[k][tr * 8 + 4];
            *(float4*)&bv[0] = *(const float4*)&Bs[k][tc * 8];
            *(float4*)&bv[4] = *(const float4*)&Bs[k][tc * 8 + 4];
#pragma unroll
            for (int i = 0; i < 8; ++i)
#pragma unroll
                for (int j = 0; j < 8; ++j) acc[i][j] += av[i] * bv[j];
        }
        __syncthreads();
    }

    float* Outb = Out + cb;
    const float* X0b = X0 + cb;
#pragma unroll
    for (int i = 0; i < 8; ++i) {
        int m = m0 + tr * 8 + i;
        float bb = bias[m];
        size_t off = (size_t)m * L + n0 + tc * 8;
        float o[8];
        if (MODE == 1) {
            float4 r0 = *(const float4*)&X0b[off];
            float4 r1 = *(const float4*)&X0b[off + 4];
            o[0] = r0.x; o[1] = r0.y; o[2] = r0.z; o[3] = r0.w;
            o[4] = r1.x; o[5] = r1.y; o[6] = r1.z; o[7] = r1.w;
        } else {
#pragma unroll
            for (int j = 0; j < 8; ++j) o[j] = 0.f;
        }
#pragma unroll
        for (int j = 0; j < 8; ++j) {
            float v = acc[i][j] + bb;
            if (MODE == 0) v = gelu_tanh(v);
            o[j] += (MODE == 0) ? (v - o[j]) : v;
        }
        *(float4*)&Outb[off]     = make_float4(o[0], o[1], o[2], o[3]);
        *(float4*)&Outb[off + 4] = make_float4(o[4], o[5], o[6], o[7]);
    }
}

// ---------------- LayerNorm over channels (skip already fused upstream) ----
// Block: 64 l-positions of one b; float2 global I/O; v staged in LDS.
__global__ __launch_bounds__(256) void ln_kernel(
    float* __restrict__ Y, const float* __restrict__ g, const float* __restrict__ be)
{
    __shared__ float v[256][64];
    __shared__ float ps[8][64], pq[8][64];
    __shared__ float smu[64], srs[64];
    const int tid = threadIdx.x;
    const int lp = tid & 31;   // l = 2*lp, 2*lp+1
    const int c0 = tid >> 5;   // 0..7, 32 channels each
    const size_t base = (size_t)blockIdx.y * 256 * 8192 + (size_t)blockIdx.x * 64 + 2 * lp;
    float sx = 0.f, sy = 0.f, qx = 0.f, qy = 0.f;
#pragma unroll 4
    for (int cc = 0; cc < 32; ++cc) {
        int c = (c0 << 5) + cc;
        float2 val = *(const float2*)&Y[base + (size_t)c * 8192];
        *(float2*)&v[c][2 * lp] = val;
        sx += val.x; sy += val.y;
        qx += val.x * val.x; qy += val.y * val.y;
    }
    ps[c0][2 * lp] = sx; ps[c0][2 * lp + 1] = sy;
    pq[c0][2 * lp] = qx; pq[c0][2 * lp + 1] = qy;
    __syncthreads();
    if (tid < 64) {
        float S_ = 0.f, Q_ = 0.f;
#pragma unroll
        for (int i = 0; i < 8; ++i) { S_ += ps[i][tid]; Q_ += pq[i][tid]; }
        float m = S_ * (1.f / 256.f);
        smu[tid] = m;
        srs[tid] = rsqrtf(Q_ * (1.f / 256.f) - m * m + 1e-5f);
    }
    __syncthreads();
    float mu0 = smu[2 * lp], mu1 = smu[2 * lp + 1];
    float rs0 = srs[2 * lp], rs1 = srs[2 * lp + 1];
#pragma unroll 4
    for (int cc = 0; cc < 32; ++cc) {
        int c = (c0 << 5) + cc;
        float2 val = *(const float2*)&v[c][2 * lp];
        float gg = g[c], bb = be[c];
        float2 out;
        out.x = (val.x - mu0) * rs0 * gg + bb;
        out.y = (val.y - mu1) * rs1 * gg + bb;
        *(float2*)&Y[base + (size_t)c * 8192] = out;
    }
}

extern "C" void kernel_launch(void* const* d_in, const int* in_sizes, int n_in,
                              void* d_out, int out_size, void* d_ws, size_t ws_size,
                              hipStream_t stream) {
    const float* x     = (const float*)d_in[0];
    const float* ab_w1 = (const float*)d_in[1];
    const float* ab_b1 = (const float*)d_in[2];
    const float* ab_w2 = (const float*)d_in[3];
    const float* ab_b2 = (const float*)d_in[4];
    const float* db_w1 = (const float*)d_in[5];
    const float* db_b1 = (const float*)d_in[6];
    const float* db_w2 = (const float*)d_in[7];
    const float* db_b2 = (const float*)d_in[8];
    const float* ln_g  = (const float*)d_in[9];
    const float* ln_b  = (const float*)d_in[10];

    const int B = 16;
    const int ROWS = B * 256;  // 4096 (b,c) rows
    float* A1 = (float*)d_ws;
    float* D1 = A1 + (size_t)B * 256 * 4096;
    float* A2 = D1 + (size_t)B * 256 * 4096;
    float* D2 = A2 + (size_t)B * 256 * 2048;
    float* A3 = D2 + (size_t)B * 256 * 2048;
    float* D3 = A3 + (size_t)B * 256 * 1024;
    float* H   = (float*)d_out;  // hidden scratch, overwritten later
    float* out = (float*)d_out;

    // ---- analysis ----
    dwt_kernel<<<dim3(4, ROWS), 256, 0, stream>>>(x, A1, D1, 12);    // 8192 -> 4096
    gemm_kernel<0><<<dim3(2, 32, B), 256, 0, stream>>>(D1, db_w1, db_b1, nullptr, H, 4096);
    gemm_kernel<1><<<dim3(2, 32, B), 256, 0, stream>>>(H, db_w2, db_b2, D1, D1, 4096);
    dwt_kernel<<<dim3(2, ROWS), 256, 0, stream>>>(A1, A2, D2, 11);   // 4096 -> 2048
    gemm_kernel<0><<<dim3(2, 16, B), 256, 0, stream>>>(D2, db_w1, db_b1, nullptr, H, 2048);
    gemm_kernel<1><<<dim3(2, 16, B), 256, 0, stream>>>(H, db_w2, db_b2, D2, D2, 2048);
    dwt_kernel<<<dim3(1, ROWS), 256, 0, stream>>>(A2, A3, D3, 10);   // 2048 -> 1024
    gemm_kernel<0><<<dim3(2, 8, B), 256, 0, stream>>>(D3, db_w1, db_b1, nullptr, H, 1024);
    gemm_kernel<1><<<dim3(2, 8, B), 256, 0, stream>>>(H, db_w2, db_b2, D3, D3, 1024);
    gemm_kernel<0><<<dim3(2, 8, B), 256, 0, stream>>>(A3, ab_w1, ab_b1, nullptr, H, 1024);
    gemm_kernel<1><<<dim3(2, 8, B), 256, 0, stream>>>(H, ab_w2, ab_b2, A3, A3, 1024);

    // ---- synthesis ----
    idwt_kernel<<<dim3(1, ROWS), 256, 0, stream>>>(A3, D3, nullptr, A2, 11);  // 1024 -> 2048
    idwt_kernel<<<dim3(2, ROWS), 256, 0, stream>>>(A2, D2, nullptr, A1, 12);  // 2048 -> 4096
    idwt_kernel<<<dim3(4, ROWS), 256, 0, stream>>>(A1, D1, x, out, 13);       // 4096 -> 8192, +skip

    // ---- layer norm (in place on d_out) ----
    ln_kernel<<<dim3(128, B), 256, 0, stream>>>(out, ln_g, ln_b);
}

// Round 3
// 480.801 us; speedup vs baseline: 2.4220x; 1.9782x over previous
//
#include <hip/hip_runtime.h>
#include <cstddef>

typedef unsigned short u16;
typedef short short8 __attribute__((ext_vector_type(8)));
typedef float f32x4 __attribute__((ext_vector_type(4)));

// db4 filters (cross-correlation taps, matching lax.conv_general_dilated)
__constant__ float c_dec_lo[8] = {
    -0.010597401785069032f, 0.0328830116668852f, 0.030841381835560764f,
    -0.18703481171888114f, -0.027983769416859854f, 0.6308807679298589f,
    0.7148465705529157f, 0.2303778133088965f};
__constant__ float c_dec_hi[8] = {
    -0.2303778133088965f, 0.7148465705529157f, -0.6308807679298589f,
    -0.027983769416859854f, 0.18703481171888114f, 0.030841381835560764f,
    -0.0328830116668852f, -0.010597401785069032f};
__constant__ float c_rec_lo[8] = {
    0.2303778133088965f, 0.7148465705529157f, 0.6308807679298589f,
    -0.027983769416859854f, -0.18703481171888114f, 0.030841381835560764f,
    0.0328830116668852f, -0.010597401785069032f};
__constant__ float c_rec_hi[8] = {
    -0.010597401785069032f, -0.0328830116668852f, 0.030841381835560764f,
    0.18703481171888114f, -0.027983769416859854f, -0.6308807679298589f,
    0.7148465705529157f, -0.2303778133088965f};

__device__ __forceinline__ float b2f(u16 v) {
    union { unsigned u; float f; } z; z.u = ((unsigned)v) << 16; return z.f;
}
__device__ __forceinline__ u16 f2b(float f) {
    union { float f; unsigned u; } z; z.f = f;
    unsigned r = z.u + 0x7fffu + ((z.u >> 16) & 1u);
    return (u16)(r >> 16);
}
__device__ __forceinline__ unsigned pk2(float a, float b) {
    return (unsigned)f2b(a) | ((unsigned)f2b(b) << 16);
}
__device__ __forceinline__ float gelu_tanh(float x) {
    float u = 0.7978845608028654f * (x + 0.044715f * x * x * x);
    float e = __expf(2.f * u);
    float t = 1.f - 2.f / (e + 1.f);
    return 0.5f * x * (1.f + t);
}

__device__ __forceinline__ float ldel(const float* p, int i) { return p[i]; }
__device__ __forceinline__ float ldel(const u16* p, int i) { return b2f(p[i]); }
__device__ __forceinline__ void ld4(const float* p, int gb, float4& v) {
    v = *(const float4*)(p + gb);
}
__device__ __forceinline__ void ld4(const u16* p, int gb, float4& v) {
    ushort4 u = *(const ushort4*)(p + gb);
    v.x = b2f(u.x); v.y = b2f(u.y); v.z = b2f(u.z); v.w = b2f(u.w);
}

// ---------------- weight pre-fragmentation: fp32 [m][k] -> bf16 MFMA A-frag order
// element j of (mt,kt,lane): A[m=mt*16+(lane&15)][k=kt*32+(lane>>4)*8+j]
// flat dst index: ((mt*8+kt)*64+lane)*8 + j
__global__ __launch_bounds__(256) void wconv_kernel(
    const float* __restrict__ s0, const float* __restrict__ s1,
    const float* __restrict__ s2, const float* __restrict__ s3,
    u16* __restrict__ dst)
{
    const float* S[4] = {s0, s1, s2, s3};
    const float* src = S[blockIdx.y];
    u16* d = dst + (size_t)blockIdx.y * 65536;
    int gid = blockIdx.x * 256 + threadIdx.x;  // 0..8191
    int lane = gid & 63;
    int kt = (gid >> 6) & 7;
    int mt = gid >> 9;
    int m = mt * 16 + (lane & 15);
    int k = kt * 32 + (lane >> 4) * 8;
    float4 v0 = *(const float4*)&src[m * 256 + k];
    float4 v1 = *(const float4*)&src[m * 256 + k + 4];
    uint4 o;
    o.x = pk2(v0.x, v0.y); o.y = pk2(v0.z, v0.w);
    o.z = pk2(v1.x, v1.y); o.w = pk2(v1.z, v1.w);
    *(uint4*)&d[(size_t)gid * 8] = o;
}

// ---------------- DWT (fp32 or bf16 in, bf16 out) ----------------
template <typename TI>
__global__ __launch_bounds__(256) void dwt_kernel(
    const TI* __restrict__ X, u16* __restrict__ LO, u16* __restrict__ HI,
    int Lout_shift)
{
    const int Lout = 1 << Lout_shift;
    const int Lin = Lout << 1;
    const int tid = threadIdx.x;
    const int T0 = blockIdx.x << 10;
    const TI* xr = X + ((size_t)blockIdx.y << (Lout_shift + 1));
    const size_t rout = (size_t)blockIdx.y * (size_t)Lout;
    __shared__ float sx[4][520];  // 514 chunks used
    const int g0 = 2 * T0 - 4;
    for (int k = tid; k < 514; k += 256) {
        int gb = g0 + 4 * k;
        float4 v;
        if (gb >= 0 && gb + 4 <= Lin) {
            ld4(xr, gb, v);
        } else {
            v.x = (gb + 0 >= 0 && gb + 0 < Lin) ? ldel(xr, gb + 0) : 0.f;
            v.y = (gb + 1 >= 0 && gb + 1 < Lin) ? ldel(xr, gb + 1) : 0.f;
            v.z = (gb + 2 >= 0 && gb + 2 < Lin) ? ldel(xr, gb + 2) : 0.f;
            v.w = (gb + 3 >= 0 && gb + 3 < Lin) ? ldel(xr, gb + 3) : 0.f;
        }
        sx[0][k] = v.x; sx[1][k] = v.y; sx[2][k] = v.z; sx[3][k] = v.w;
    }
    __syncthreads();
    const int u = tid;  // outputs t = T0+4u..+3; li in [8u+1, 8u+14]
    float xv[14];
#pragma unroll
    for (int n = 0; n < 14; ++n)
        xv[n] = sx[(1 + n) & 3][2 * u + ((1 + n) >> 2)];
    float lo[4], hi[4];
#pragma unroll
    for (int e = 0; e < 4; ++e) {
        float l = 0.f, h = 0.f;
#pragma unroll
        for (int kk = 0; kk < 8; ++kk) {
            float v = xv[2 * e + kk];
            l += c_dec_lo[kk] * v;
            h += c_dec_hi[kk] * v;
        }
        lo[e] = l; hi[e] = h;
    }
    size_t o = rout + T0 + 4 * u;
    uint2 pl; pl.x = pk2(lo[0], lo[1]); pl.y = pk2(lo[2], lo[3]);
    uint2 ph; ph.x = pk2(hi[0], hi[1]); ph.y = pk2(hi[2], hi[3]);
    *(uint2*)&LO[o] = pl;
    *(uint2*)&HI[o] = ph;
}

// ---------------- IDWT (bf16 in, bf16 out) ----------------
__global__ __launch_bounds__(256) void idwt_kernel(
    const u16* __restrict__ A, const u16* __restrict__ D,
    u16* __restrict__ Y, int Lout_shift)
{
    const int Lout = 1 << Lout_shift;
    const int Lin = Lout >> 1;
    const int tid = threadIdx.x;
    const int T0 = blockIdx.x << 11;
    const size_t rin = (size_t)blockIdx.y * (size_t)Lin;
    const size_t rout = (size_t)blockIdx.y * (size_t)Lout;
    __shared__ float sa[4][264], sd[4][264];  // 258 chunks used
    const int g0 = (T0 >> 1) - 4;
    for (int k = tid; k < 258; k += 256) {
        int gb = g0 + 4 * k;
        float4 va, vd;
        if (gb >= 0 && gb + 4 <= Lin) {
            ld4(A + rin, gb, va);
            ld4(D + rin, gb, vd);
        } else {
            const u16* a = A + rin;
            const u16* d = D + rin;
            va.x = (gb + 0 >= 0 && gb + 0 < Lin) ? b2f(a[gb + 0]) : 0.f;
            va.y = (gb + 1 >= 0 && gb + 1 < Lin) ? b2f(a[gb + 1]) : 0.f;
            va.z = (gb + 2 >= 0 && gb + 2 < Lin) ? b2f(a[gb + 2]) : 0.f;
            va.w = (gb + 3 >= 0 && gb + 3 < Lin) ? b2f(a[gb + 3]) : 0.f;
            vd.x = (gb + 0 >= 0 && gb + 0 < Lin) ? b2f(d[gb + 0]) : 0.f;
            vd.y = (gb + 1 >= 0 && gb + 1 < Lin) ? b2f(d[gb + 1]) : 0.f;
            vd.z = (gb + 2 >= 0 && gb + 2 < Lin) ? b2f(d[gb + 2]) : 0.f;
            vd.w = (gb + 3 >= 0 && gb + 3 < Lin) ? b2f(d[gb + 3]) : 0.f;
        }
        sa[0][k] = va.x; sa[1][k] = va.y; sa[2][k] = va.z; sa[3][k] = va.w;
        sd[0][k] = vd.x; sd[1][k] = vd.y; sd[2][k] = vd.z; sd[3][k] = vd.w;
    }
    __syncthreads();
    const int u = tid;  // outputs t = T0+8u..+7; li in [4u+2, 4u+9]
    float Aa[8], Dd[8];
#pragma unroll
    for (int n = 0; n < 8; ++n) {
        int li = 4 * u + 2 + n;
        Aa[n] = sa[(2 + n) & 3][li >> 2];
        Dd[n] = sd[(2 + n) & 3][li >> 2];
    }
    float o[8];
#pragma unroll
    for (int e = 0; e < 4; ++e) {
        o[2 * e] =
            c_rec_lo[1] * Aa[e + 3] + c_rec_lo[3] * Aa[e + 2] +
            c_rec_lo[5] * Aa[e + 1] + c_rec_lo[7] * Aa[e] +
            c_rec_hi[1] * Dd[e + 3] + c_rec_hi[3] * Dd[e + 2] +
            c_rec_hi[5] * Dd[e + 1] + c_rec_hi[7] * Dd[e];
        o[2 * e + 1] =
            c_rec_lo[0] * Aa[e + 4] + c_rec_lo[2] * Aa[e + 3] +
            c_rec_lo[4] * Aa[e + 2] + c_rec_lo[6] * Aa[e + 1] +
            c_rec_hi[0] * Dd[e + 4] + c_rec_hi[2] * Dd[e + 3] +
            c_rec_hi[4] * Dd[e + 2] + c_rec_hi[6] * Dd[e + 1];
    }
    size_t ob = rout + T0 + 8 * u;
    uint4 pv;
    pv.x = pk2(o[0], o[1]); pv.y = pk2(o[2], o[3]);
    pv.z = pk2(o[4], o[5]); pv.w = pk2(o[6], o[7]);
    *(uint4*)&Y[ob] = pv;
}

// ---------------- fused ResConv1dBlock (bf16 MFMA) ----------------
// Out[b,:,n-strip] = X + W2 @ gelu(W1 @ X + b1) + b2, strip of 64 columns.
// Xs/Hs in LDS as [n][k] (k contiguous, KPAD stride). In-place safe (column blocks).
#define KPAD 264

__device__ __forceinline__ void gemm_phase(
    const u16* __restrict__ Wf, const u16* __restrict__ Bs,
    int lane, int w, int fl, int fq, f32x4 acc[4][4])
{
    const u16* wb = Wf + (size_t)(4 * w) * 4096 + (size_t)lane * 8;
    short8 a[4], an[4];
#pragma unroll
    for (int i = 0; i < 4; ++i)
        a[i] = *(const short8*)(wb + i * 4096);
#pragma unroll
    for (int kt = 0; kt < 8; ++kt) {
        if (kt < 7) {
#pragma unroll
            for (int i = 0; i < 4; ++i)
                an[i] = *(const short8*)(wb + i * 4096 + (kt + 1) * 512);
        }
        short8 bf[4];
#pragma unroll
        for (int nt = 0; nt < 4; ++nt)
            bf[nt] = *(const short8*)&Bs[(nt * 16 + fl) * KPAD + kt * 32 + fq * 8];
#pragma unroll
        for (int i = 0; i < 4; ++i)
#pragma unroll
            for (int nt = 0; nt < 4; ++nt)
                acc[i][nt] = __builtin_amdgcn_mfma_f32_16x16x32_bf16(
                    a[i], bf[nt], acc[i][nt], 0, 0, 0);
#pragma unroll
        for (int i = 0; i < 4; ++i) a[i] = an[i];
    }
}

__global__ __launch_bounds__(256, 2) void rb_kernel(
    const u16* __restrict__ Xg, u16* __restrict__ Outg,
    const u16* __restrict__ W1f, const float* __restrict__ b1,
    const u16* __restrict__ W2f, const float* __restrict__ b2, int L)
{
    __shared__ u16 Xs[64 * KPAD];
    __shared__ u16 Hs[64 * KPAD];
    const int tid = threadIdx.x;
    const int lane = tid & 63;
    const int w = tid >> 6;
    const int fl = lane & 15;
    const int fq = lane >> 4;
    const int n0 = blockIdx.x * 64;
    const size_t bbase = (size_t)blockIdx.y * 256 * (size_t)L;

    // ---- stage X: global [k][n] bf16 -> Xs[n][k] (4x4 register transpose) ----
    {
        const int nq = tid & 15;
        const int kq = tid >> 4;  // 0..15
        const u16* src = Xg + bbase + n0 + 4 * nq;
#pragma unroll
        for (int p = 0; p < 4; ++p) {
            int kb = p * 64 + kq * 4;
            uint2 r0 = *(const uint2*)(src + (size_t)(kb + 0) * L);
            uint2 r1 = *(const uint2*)(src + (size_t)(kb + 1) * L);
            uint2 r2 = *(const uint2*)(src + (size_t)(kb + 2) * L);
            uint2 r3 = *(const uint2*)(src + (size_t)(kb + 3) * L);
#pragma unroll
            for (int j = 0; j < 4; ++j) {
                unsigned e0 = ((j < 2 ? r0.x : r0.y) >> ((j & 1) * 16)) & 0xffffu;
                unsigned e1 = ((j < 2 ? r1.x : r1.y) >> ((j & 1) * 16)) & 0xffffu;
                unsigned e2 = ((j < 2 ? r2.x : r2.y) >> ((j & 1) * 16)) & 0xffffu;
                unsigned e3 = ((j < 2 ? r3.x : r3.y) >> ((j & 1) * 16)) & 0xffffu;
                uint2 o; o.x = e0 | (e1 << 16); o.y = e2 | (e3 << 16);
                *(uint2*)&Xs[(4 * nq + j) * KPAD + kb] = o;
            }
        }
    }
    __syncthreads();

    // ---- GEMM1: H = gelu(W1 @ X + b1) ----
    f32x4 acc[4][4];
#pragma unroll
    for (int i = 0; i < 4; ++i)
#pragma unroll
        for (int nt = 0; nt < 4; ++nt) acc[i][nt] = (f32x4){0.f, 0.f, 0.f, 0.f};
    gemm_phase(W1f, Xs, lane, w, fl, fq, acc);
#pragma unroll
    for (int i = 0; i < 4; ++i) {
        const int m0 = 64 * w + i * 16 + fq * 4;
        float4 bv = *(const float4*)&b1[m0];
#pragma unroll
        for (int nt = 0; nt < 4; ++nt) {
            float v0 = gelu_tanh(acc[i][nt][0] + bv.x);
            float v1 = gelu_tanh(acc[i][nt][1] + bv.y);
            float v2 = gelu_tanh(acc[i][nt][2] + bv.z);
            float v3 = gelu_tanh(acc[i][nt][3] + bv.w);
            uint2 o; o.x = pk2(v0, v1); o.y = pk2(v2, v3);
            *(uint2*)&Hs[(nt * 16 + fl) * KPAD + m0] = o;
        }
    }
    __syncthreads();

    // ---- GEMM2: Out = X0 + W2 @ H + b2 ----
#pragma unroll
    for (int i = 0; i < 4; ++i)
#pragma unroll
        for (int nt = 0; nt < 4; ++nt) acc[i][nt] = (f32x4){0.f, 0.f, 0.f, 0.f};
    gemm_phase(W2f, Hs, lane, w, fl, fq, acc);

    uint2 outv[4][4];
#pragma unroll
    for (int i = 0; i < 4; ++i) {
        const int m0 = 64 * w + i * 16 + fq * 4;
        float4 bv = *(const float4*)&b2[m0];
#pragma unroll
        for (int nt = 0; nt < 4; ++nt) {
            const int n = nt * 16 + fl;
            uint2 x0 = *(const uint2*)&Xs[n * KPAD + m0];
            float v0 = acc[i][nt][0] + bv.x + b2f((u16)(x0.x & 0xffffu));
            float v1 = acc[i][nt][1] + bv.y + b2f((u16)(x0.x >> 16));
            float v2 = acc[i][nt][2] + bv.z + b2f((u16)(x0.y & 0xffffu));
            float v3 = acc[i][nt][3] + bv.w + b2f((u16)(x0.y >> 16));
            outv[i][nt].x = pk2(v0, v1);
            outv[i][nt].y = pk2(v2, v3);
        }
    }
    __syncthreads();  // all waves finished reading Hs
#pragma unroll
    for (int i = 0; i < 4; ++i) {
        const int m0 = 64 * w + i * 16 + fq * 4;
#pragma unroll
        for (int nt = 0; nt < 4; ++nt)
            *(uint2*)&Hs[(nt * 16 + fl) * KPAD + m0] = outv[i][nt];
    }
    __syncthreads();

    // ---- coalesced store: Hs[n][m] -> Out[m][n] ----
    {
        const int n = tid & 63;
        const int mB = (tid >> 6) * 64;
        u16* dst = Outg + bbase + n0 + n;
#pragma unroll
        for (int mi = 0; mi < 16; ++mi) {
            int m = mB + mi * 4;
            uint2 v = *(const uint2*)&Hs[n * KPAD + m];
            dst[(size_t)(m + 0) * L] = (u16)(v.x & 0xffffu);
            dst[(size_t)(m + 1) * L] = (u16)(v.x >> 16);
            dst[(size_t)(m + 2) * L] = (u16)(v.y & 0xffffu);
            dst[(size_t)(m + 3) * L] = (u16)(v.y >> 16);
        }
    }
}

// ---------------- LayerNorm over channels: out = LN(y + x) ----------------
__global__ __launch_bounds__(256) void ln_kernel(
    const u16* __restrict__ Yb, const float* __restrict__ X,
    float* __restrict__ O, const float* __restrict__ g, const float* __restrict__ be)
{
    __shared__ float v[256][64];
    __shared__ float ps[8][64], pq[8][64];
    __shared__ float smu[64], srs[64];
    const int tid = threadIdx.x;
    const int lp = tid & 31;
    const int c0 = tid >> 5;
    const size_t base = (size_t)blockIdx.y * 256 * 8192 + (size_t)blockIdx.x * 64 + 2 * lp;
    float sx = 0.f, sy = 0.f, qx = 0.f, qy = 0.f;
#pragma unroll 4
    for (int cc = 0; cc < 32; ++cc) {
        int c = (c0 << 5) + cc;
        size_t a = base + (size_t)c * 8192;
        ushort2 y2 = *(const ushort2*)&Yb[a];
        float2 x2 = *(const float2*)&X[a];
        float2 val; val.x = b2f(y2.x) + x2.x; val.y = b2f(y2.y) + x2.y;
        *(float2*)&v[c][2 * lp] = val;
        sx += val.x; sy += val.y;
        qx += val.x * val.x; qy += val.y * val.y;
    }
    ps[c0][2 * lp] = sx; ps[c0][2 * lp + 1] = sy;
    pq[c0][2 * lp] = qx; pq[c0][2 * lp + 1] = qy;
    __syncthreads();
    if (tid < 64) {
        float S_ = 0.f, Q_ = 0.f;
#pragma unroll
        for (int i = 0; i < 8; ++i) { S_ += ps[i][tid]; Q_ += pq[i][tid]; }
        float m = S_ * (1.f / 256.f);
        smu[tid] = m;
        srs[tid] = rsqrtf(Q_ * (1.f / 256.f) - m * m + 1e-5f);
    }
    __syncthreads();
    float mu0 = smu[2 * lp], mu1 = smu[2 * lp + 1];
    float rs0 = srs[2 * lp], rs1 = srs[2 * lp + 1];
#pragma unroll 4
    for (int cc = 0; cc < 32; ++cc) {
        int c = (c0 << 5) + cc;
        size_t a = base + (size_t)c * 8192;
        float2 val = *(const float2*)&v[c][2 * lp];
        float gg = g[c], bb = be[c];
        float2 out;
        out.x = (val.x - mu0) * rs0 * gg + bb;
        out.y = (val.y - mu1) * rs1 * gg + bb;
        *(float2*)&O[a] = out;
    }
}

extern "C" void kernel_launch(void* const* d_in, const int* in_sizes, int n_in,
                              void* d_out, int out_size, void* d_ws, size_t ws_size,
                              hipStream_t stream) {
    const float* x     = (const float*)d_in[0];
    const float* ab_w1 = (const float*)d_in[1];
    const float* ab_b1 = (const float*)d_in[2];
    const float* ab_w2 = (const float*)d_in[3];
    const float* ab_b2 = (const float*)d_in[4];
    const float* db_w1 = (const float*)d_in[5];
    const float* db_b1 = (const float*)d_in[6];
    const float* db_w2 = (const float*)d_in[7];
    const float* db_b2 = (const float*)d_in[8];
    const float* ln_g  = (const float*)d_in[9];
    const float* ln_b  = (const float*)d_in[10];

    // workspace (bf16): A1,D1 @4096; A2,D2 @2048; A3,D3 @1024; Y @8192; Wf ~ 185 MiB
    u16* A1 = (u16*)d_ws;
    u16* D1 = A1 + (size_t)16 * 256 * 4096;
    u16* A2 = D1 + (size_t)16 * 256 * 4096;
    u16* D2 = A2 + (size_t)16 * 256 * 2048;
    u16* A3 = D2 + (size_t)16 * 256 * 2048;
    u16* D3 = A3 + (size_t)16 * 256 * 1024;
    u16* Yb = D3 + (size_t)16 * 256 * 1024;
    u16* Wf = Yb + (size_t)16 * 256 * 8192;
    u16* Wdb1 = Wf;
    u16* Wdb2 = Wf + 65536;
    u16* Wab1 = Wf + 131072;
    u16* Wab2 = Wf + 196608;

    wconv_kernel<<<dim3(32, 4), 256, 0, stream>>>(db_w1, db_w2, ab_w1, ab_w2, Wf);

    // ---- analysis ----
    dwt_kernel<float><<<dim3(4, 4096), 256, 0, stream>>>(x, A1, D1, 12);   // 8192->4096
    rb_kernel<<<dim3(64, 16), 256, 0, stream>>>(D1, D1, Wdb1, db_b1, Wdb2, db_b2, 4096);
    dwt_kernel<u16><<<dim3(2, 4096), 256, 0, stream>>>(A1, A2, D2, 11);    // 4096->2048
    rb_kernel<<<dim3(32, 16), 256, 0, stream>>>(D2, D2, Wdb1, db_b1, Wdb2, db_b2, 2048);
    dwt_kernel<u16><<<dim3(1, 4096), 256, 0, stream>>>(A2, A3, D3, 10);    // 2048->1024
    rb_kernel<<<dim3(16, 16), 256, 0, stream>>>(D3, D3, Wdb1, db_b1, Wdb2, db_b2, 1024);
    rb_kernel<<<dim3(16, 16), 256, 0, stream>>>(A3, A3, Wab1, ab_b1, Wab2, ab_b2, 1024);

    // ---- synthesis (A2, A1 slots reused as scratch) ----
    idwt_kernel<<<dim3(1, 4096), 256, 0, stream>>>(A3, D3, A2, 11);  // 1024->2048
    idwt_kernel<<<dim3(2, 4096), 256, 0, stream>>>(A2, D2, A1, 12);  // 2048->4096
    idwt_kernel<<<dim3(4, 4096), 256, 0, stream>>>(A1, D1, Yb, 13);  // 4096->8192

    // ---- skip + layer norm -> d_out (fp32) ----
    ln_kernel<<<dim3(128, 16), 256, 0, stream>>>(Yb, x, (float*)d_out, ln_g, ln_b);
}